// Round 3
// baseline (784.624 us; speedup 1.0000x reference)
//
#include <hip/hip_runtime.h>
#include <hip/hip_fp16.h>

// GCN VGAE encoder:
//   h  = relu((A @ x) @ W1 + b1)          [associativity: A(xW) == (Ax)W]
//   mu = (A @ h) @ Wmu + bmu ; lv = (A @ h) @ Wlv + blv
// A = D^-1/2 (Adj + I) D^-1/2, deg on dst side.
//
// R3 changes vs R2 (theory: agg kernels latency/fabric-bound on gather bytes;
// fill_csr writeback-bound on random 8B scatters):
//  * gather tables in fp16 (x and h), fp32 accumulate: halves gather bytes
//    and doubles effective L2 residency (12.8MB table).
//  * 8 edges in flight per wave (8 lanes/edge, 16B/lane = full 128B row).
//  * CSR fill split into bucketed two-phase scatter: phase A to 128-node
//    bucket regions (bucket offsets are row_ptr[128b] -- free), phase B one
//    block per bucket with LDS cursors; all writes land in small windows.

#define BKT_SHIFT 7
#define BKT_NODES 128

__global__ __launch_bounds__(256) void count_edges(const int* __restrict__ dst,
                                                   int* __restrict__ counts, int E) {
  int e = blockIdx.x * blockDim.x + threadIdx.x;
  if (e < E) atomicAdd(&counts[dst[e]], 1);
}

// Pass 1: per-block sums of counts (1024 elements/block).
__global__ __launch_bounds__(1024) void block_sums(const int* __restrict__ counts,
                                                   int* __restrict__ bsum, int n) {
  __shared__ int s[1024];
  int t = threadIdx.x;
  int i = blockIdx.x * 1024 + t;
  s[t] = (i < n) ? counts[i] : 0;
  __syncthreads();
  for (int off = 512; off > 0; off >>= 1) {
    if (t < off) s[t] += s[t + off];
    __syncthreads();
  }
  if (t == 0) bsum[blockIdx.x] = s[0];
}

// Pass 2: single-block exclusive scan over nb (<=1024) block sums, in place.
__global__ __launch_bounds__(1024) void scan_bsums(int* __restrict__ bsum, int nb) {
  __shared__ int s[1024];
  int t = threadIdx.x;
  int v = (t < nb) ? bsum[t] : 0;
  s[t] = v;
  __syncthreads();
  for (int off = 1; off < 1024; off <<= 1) {
    int u = (t >= off) ? s[t - off] : 0;
    __syncthreads();
    s[t] += u;
    __syncthreads();
  }
  if (t < nb) bsum[t] = s[t] - v;  // exclusive
}

// Pass 3: in-block inclusive scan + block offset -> row_ptr/dinv.
__global__ __launch_bounds__(1024) void scan_final(const int* __restrict__ counts,
                                                   const int* __restrict__ bofs,
                                                   int* __restrict__ row_ptr,
                                                   float* __restrict__ dinv,
                                                   int n, int E) {
  __shared__ int s[1024];
  int t = threadIdx.x;
  int i = blockIdx.x * 1024 + t;
  int c = (i < n) ? counts[i] : 0;
  s[t] = c;
  __syncthreads();
  for (int off = 1; off < 1024; off <<= 1) {
    int u = (t >= off) ? s[t - off] : 0;
    __syncthreads();
    s[t] += u;
    __syncthreads();
  }
  if (i < n) {
    int excl = bofs[blockIdx.x] + s[t] - c;
    row_ptr[i] = excl;
    dinv[i] = rsqrtf(1.0f + (float)c);  // deg includes self-loop
  }
  if (i == 0) row_ptr[n] = E;
}

// Bucket cursors = row_ptr at each bucket's first node (buckets are
// contiguous dst ranges, so no separate bucket scan is needed).
__global__ __launch_bounds__(256) void init_bktcur(const int* __restrict__ row_ptr,
                                                   int* __restrict__ bktcur, int nbk) {
  int b = blockIdx.x * blockDim.x + threadIdx.x;
  if (b < nbk) bktcur[b] = row_ptr[b << BKT_SHIFT];
}

// Phase A: scatter {src,dst} into per-bucket regions. Active write frontier =
// nbk cache lines (~50KB) -> L2-resident, minimal writeback amplification.
__global__ __launch_bounds__(256) void scatter_bucket(const int* __restrict__ src,
                                                      const int* __restrict__ dst,
                                                      int* __restrict__ bktcur,
                                                      int2* __restrict__ tmp, int E) {
  int e = blockIdx.x * blockDim.x + threadIdx.x;
  if (e < E) {
    int s = src[e];
    int d = dst[e];
    int pos = atomicAdd(&bktcur[d >> BKT_SHIFT], 1);
    tmp[pos] = make_int2(s, d);
  }
}

// Phase B: one block per bucket; LDS cursors (no global atomics); final
// positions land inside the bucket's ~16KB window of `pairs`.
__global__ __launch_bounds__(256) void scatter_final(const int2* __restrict__ tmp,
                                                     const int* __restrict__ row_ptr,
                                                     const float* __restrict__ dinv,
                                                     int2* __restrict__ pairs, int n) {
  __shared__ int cur[BKT_NODES];
  const int b = blockIdx.x;
  const int node0 = b << BKT_SHIFT;
  const int t = threadIdx.x;
  if (t < BKT_NODES) {
    int node = node0 + t;
    cur[t] = (node < n) ? row_ptr[node] : 0;
  }
  __syncthreads();
  int node_end = node0 + BKT_NODES;
  if (node_end > n) node_end = n;
  const int start = row_ptr[node0];
  const int end = row_ptr[node_end];
  for (int e = start + t; e < end; e += 256) {
    int2 p = tmp[e];
    int pos = atomicAdd(&cur[p.y - node0], 1);
    pairs[pos] = make_int2(p.x, __float_as_int(dinv[p.x]));
  }
}

// fp32 -> fp16 cast of the gather table (x), vectorized.
__global__ __launch_bounds__(256) void cast_f16(const float* __restrict__ x,
                                                __half* __restrict__ xh, int n4) {
  int i = blockIdx.x * blockDim.x + threadIdx.x;
  if (i < n4) {
    float4 v = ((const float4*)x)[i];
    __half2 h0 = __floats2half2_rn(v.x, v.y);
    __half2 h1 = __floats2half2_rn(v.z, v.w);
    __half2* o = (__half2*)(xh + (size_t)i * 4);
    o[0] = h0;
    o[1] = h1;
  }
}

// Layer 1: y = A @ x (pull, fp16 gather / fp32 accumulate),
// h = half(relu(y @ W1 + b1)). One wave per row; lane = 8*g + q:
// group g handles edge slot g (8 edges/iter), lane loads 16B = 8 halves
// covering features q*8 .. q*8+7.
__global__ __launch_bounds__(256) void agg_layer1(const __half* __restrict__ xh,
                                                  const int2* __restrict__ pairs,
                                                  const int* __restrict__ row_ptr,
                                                  const float* __restrict__ W1,
                                                  const float* __restrict__ b1,
                                                  __half* __restrict__ h, int n) {
  const int lane = threadIdx.x & 63;
  const int g = lane >> 3;  // edge slot 0..7
  const int q = lane & 7;   // feature octet
  float w[64];
#pragma unroll
  for (int k = 0; k < 64; ++k) w[k] = W1[k * 64 + lane];  // column `lane`
  const float bias = b1[lane];

  int wid = blockIdx.x * (blockDim.x >> 6) + (threadIdx.x >> 6);
  int nw = gridDim.x * (blockDim.x >> 6);
  for (int i = wid; i < n; i += nw) {
    const int start = row_ptr[i];
    const int end = row_ptr[i + 1];
    float a0 = 0, a1 = 0, a2 = 0, a3 = 0, a4 = 0, a5 = 0, a6 = 0, a7 = 0;
    for (int base = start; base < end; base += 8) {
      int2 p = make_int2(i, 0);  // tail: ws = 0, safe index
      if (base + g < end) p = pairs[base + g];
      const float ws = __int_as_float(p.y);
      const float4 r = *(const float4*)(xh + (size_t)p.x * 64 + q * 8);
      const __half2* hp = (const __half2*)&r;
      float2 f0 = __half22float2(hp[0]), f1 = __half22float2(hp[1]);
      float2 f2 = __half22float2(hp[2]), f3 = __half22float2(hp[3]);
      a0 += ws * f0.x; a1 += ws * f0.y; a2 += ws * f1.x; a3 += ws * f1.y;
      a4 += ws * f2.x; a5 += ws * f2.y; a6 += ws * f3.x; a7 += ws * f3.y;
    }
    // reduce the 8 edge-groups: butterfly over lane^8, ^16, ^32
#pragma unroll
    for (int off = 8; off <= 32; off <<= 1) {
      a0 += __shfl_xor(a0, off); a1 += __shfl_xor(a1, off);
      a2 += __shfl_xor(a2, off); a3 += __shfl_xor(a3, off);
      a4 += __shfl_xor(a4, off); a5 += __shfl_xor(a5, off);
      a6 += __shfl_xor(a6, off); a7 += __shfl_xor(a7, off);
    }
    const float di = rsqrtf((float)(1 + end - start));
    const float dii = di * di;
    const float4 r = *(const float4*)(xh + (size_t)i * 64 + q * 8);
    const __half2* hp = (const __half2*)&r;
    float2 s0 = __half22float2(hp[0]), s1 = __half22float2(hp[1]);
    float2 s2 = __half22float2(hp[2]), s3 = __half22float2(hp[3]);
    float y0 = di * a0 + dii * s0.x, y1 = di * a1 + dii * s0.y;
    float y2 = di * a2 + dii * s1.x, y3 = di * a3 + dii * s1.y;
    float y4 = di * a4 + dii * s2.x, y5 = di * a5 + dii * s2.y;
    float y6 = di * a6 + dii * s3.x, y7 = di * a7 + dii * s3.y;
    // dense epilogue: out[lane] = b1[lane] + sum_k y[k] * W1[k][lane]
    // feature k = 8*kq + c lives (identically in all groups) in lane kq.
    float out = bias;
#pragma unroll
    for (int kq = 0; kq < 8; ++kq) {
      out += __shfl(y0, kq) * w[8 * kq + 0];
      out += __shfl(y1, kq) * w[8 * kq + 1];
      out += __shfl(y2, kq) * w[8 * kq + 2];
      out += __shfl(y3, kq) * w[8 * kq + 3];
      out += __shfl(y4, kq) * w[8 * kq + 4];
      out += __shfl(y5, kq) * w[8 * kq + 5];
      out += __shfl(y6, kq) * w[8 * kq + 6];
      out += __shfl(y7, kq) * w[8 * kq + 7];
    }
    h[(size_t)i * 64 + lane] = __float2half(fmaxf(out, 0.f));
  }
}

// Layer 2: y = A @ h; mu = y@Wmu + bmu (lanes 0-31), lv = y@Wlv + blv (32-63).
__global__ __launch_bounds__(256) void agg_layer2(const __half* __restrict__ hin,
                                                  const int2* __restrict__ pairs,
                                                  const int* __restrict__ row_ptr,
                                                  const float* __restrict__ Wmu,
                                                  const float* __restrict__ bmu,
                                                  const float* __restrict__ Wlv,
                                                  const float* __restrict__ blv,
                                                  float* __restrict__ out_mu,
                                                  float* __restrict__ out_lv, int n) {
  const int lane = threadIdx.x & 63;
  const int g = lane >> 3;
  const int q = lane & 7;
  const int col = lane & 31;
  const float* Wsel = (lane < 32) ? Wmu : Wlv;
  float w[64];
#pragma unroll
  for (int k = 0; k < 64; ++k) w[k] = Wsel[k * 32 + col];
  const float bias = (lane < 32) ? bmu[col] : blv[col];

  int wid = blockIdx.x * (blockDim.x >> 6) + (threadIdx.x >> 6);
  int nw = gridDim.x * (blockDim.x >> 6);
  for (int i = wid; i < n; i += nw) {
    const int start = row_ptr[i];
    const int end = row_ptr[i + 1];
    float a0 = 0, a1 = 0, a2 = 0, a3 = 0, a4 = 0, a5 = 0, a6 = 0, a7 = 0;
    for (int base = start; base < end; base += 8) {
      int2 p = make_int2(i, 0);
      if (base + g < end) p = pairs[base + g];
      const float ws = __int_as_float(p.y);
      const float4 r = *(const float4*)(hin + (size_t)p.x * 64 + q * 8);
      const __half2* hp = (const __half2*)&r;
      float2 f0 = __half22float2(hp[0]), f1 = __half22float2(hp[1]);
      float2 f2 = __half22float2(hp[2]), f3 = __half22float2(hp[3]);
      a0 += ws * f0.x; a1 += ws * f0.y; a2 += ws * f1.x; a3 += ws * f1.y;
      a4 += ws * f2.x; a5 += ws * f2.y; a6 += ws * f3.x; a7 += ws * f3.y;
    }
#pragma unroll
    for (int off = 8; off <= 32; off <<= 1) {
      a0 += __shfl_xor(a0, off); a1 += __shfl_xor(a1, off);
      a2 += __shfl_xor(a2, off); a3 += __shfl_xor(a3, off);
      a4 += __shfl_xor(a4, off); a5 += __shfl_xor(a5, off);
      a6 += __shfl_xor(a6, off); a7 += __shfl_xor(a7, off);
    }
    const float di = rsqrtf((float)(1 + end - start));
    const float dii = di * di;
    const float4 r = *(const float4*)(hin + (size_t)i * 64 + q * 8);
    const __half2* hp = (const __half2*)&r;
    float2 s0 = __half22float2(hp[0]), s1 = __half22float2(hp[1]);
    float2 s2 = __half22float2(hp[2]), s3 = __half22float2(hp[3]);
    float y0 = di * a0 + dii * s0.x, y1 = di * a1 + dii * s0.y;
    float y2 = di * a2 + dii * s1.x, y3 = di * a3 + dii * s1.y;
    float y4 = di * a4 + dii * s2.x, y5 = di * a5 + dii * s2.y;
    float y6 = di * a6 + dii * s3.x, y7 = di * a7 + dii * s3.y;
    float out = bias;
#pragma unroll
    for (int kq = 0; kq < 8; ++kq) {
      out += __shfl(y0, kq) * w[8 * kq + 0];
      out += __shfl(y1, kq) * w[8 * kq + 1];
      out += __shfl(y2, kq) * w[8 * kq + 2];
      out += __shfl(y3, kq) * w[8 * kq + 3];
      out += __shfl(y4, kq) * w[8 * kq + 4];
      out += __shfl(y5, kq) * w[8 * kq + 5];
      out += __shfl(y6, kq) * w[8 * kq + 6];
      out += __shfl(y7, kq) * w[8 * kq + 7];
    }
    if (lane < 32)
      out_mu[(size_t)i * 32 + col] = out;
    else
      out_lv[(size_t)i * 32 + col] = out;
  }
}

extern "C" void kernel_launch(void* const* d_in, const int* in_sizes, int n_in,
                              void* d_out, int out_size, void* d_ws, size_t ws_size,
                              hipStream_t stream) {
  const float* x = (const float*)d_in[0];
  const int* ei = (const int*)d_in[1];  // [2, E] row-major int32
  const float* W1 = (const float*)d_in[2];
  const float* b1 = (const float*)d_in[3];
  const float* Wmu = (const float*)d_in[4];
  const float* bmu = (const float*)d_in[5];
  const float* Wlv = (const float*)d_in[6];
  const float* blv = (const float*)d_in[7];

  const int N = in_sizes[0] / 64;
  const int E = in_sizes[1] / 2;
  const int* src = ei;
  const int* dst = ei + E;

  auto align256 = [](size_t v) { return (v + 255) & ~(size_t)255; };
  char* p = (char*)d_ws;
  int* counts = (int*)p;    p += align256((size_t)N * 4);
  int* row_ptr = (int*)p;   p += align256((size_t)(N + 1) * 4);
  float* dinv = (float*)p;  p += align256((size_t)N * 4);
  int* bsum = (int*)p;      p += align256((size_t)1024 * 4);
  int* bktcur = (int*)p;    p += align256((size_t)1024 * 4);
  int2* tmp = (int2*)p;     // aliased: tmp dead after scatter_final, h written in agg1
  __half* h = (__half*)p;   p += align256((size_t)E * 8);  // E*8 >= N*64*2
  int2* pairs = (int2*)p;   p += align256((size_t)E * 8);
  __half* xh = (__half*)p;  p += align256((size_t)N * 64 * 2);

  float* out_mu = (float*)d_out;
  float* out_lv = out_mu + (size_t)N * 32;

  const int NB = (N + 1023) / 1024;               // scan blocks (<=1024)
  const int NBK = (N + BKT_NODES - 1) / BKT_NODES;  // buckets

  hipMemsetAsync(counts, 0, (size_t)N * 4, stream);
  count_edges<<<(E + 255) / 256, 256, 0, stream>>>(dst, counts, E);
  block_sums<<<NB, 1024, 0, stream>>>(counts, bsum, N);
  scan_bsums<<<1, 1024, 0, stream>>>(bsum, NB);
  scan_final<<<NB, 1024, 0, stream>>>(counts, bsum, row_ptr, dinv, N, E);
  init_bktcur<<<(NBK + 255) / 256, 256, 0, stream>>>(row_ptr, bktcur, NBK);
  scatter_bucket<<<(E + 255) / 256, 256, 0, stream>>>(src, dst, bktcur, tmp, E);
  scatter_final<<<NBK, 256, 0, stream>>>(tmp, row_ptr, dinv, pairs, N);
  cast_f16<<<((N * 64 / 4) + 255) / 256, 256, 0, stream>>>(x, xh, N * 64 / 4);

  const int blocks = 4096;  // 16384 waves grid-striding 100k rows
  agg_layer1<<<blocks, 256, 0, stream>>>(xh, pairs, row_ptr, W1, b1, h, N);
  agg_layer2<<<blocks, 256, 0, stream>>>(h, pairs, row_ptr, Wmu, bmu, Wlv, blv,
                                         out_mu, out_lv, N);
}

// Round 4
// 500.101 us; speedup vs baseline: 1.5689x; 1.5689x over previous
//
#include <hip/hip_runtime.h>
#include <hip/hip_fp16.h>

// GCN VGAE encoder:
//   h  = relu((A @ x) @ W1 + b1)          [associativity: A(xW) == (Ax)W]
//   mu = (A @ h) @ Wmu + bmu ; lv = (A @ h) @ Wlv + blv
// A = D^-1/2 (Adj + I) D^-1/2, deg on dst side.
//
// R4: revert bucketed scatter (R3: 1.6M atomics / 782 cursors = serialized
// chains, 378us) to per-node cursors (100k cursors, contention-free).
// dinv[src] is per-src, so fold it into the gather tables:
//   xs[s] = dinv[s]*x[s]; hs[i] = dinv[i]*relu(...)  =>
//   y_i = dinv_i * (sum_e xs[src_e] + xs[i])
// Pairs payload shrinks to 4B (src only), fill loses the random dinv gather,
// agg hot loop loses the per-edge weight. Row N of xs/hs is a zero sentinel
// for tail lanes.

__global__ __launch_bounds__(256) void count_edges(const int* __restrict__ dst,
                                                   int* __restrict__ counts, int E) {
  int e = blockIdx.x * blockDim.x + threadIdx.x;
  if (e < E) atomicAdd(&counts[dst[e]], 1);
}

// Pass 1: per-block sums of counts (1024 elements/block).
__global__ __launch_bounds__(1024) void block_sums(const int* __restrict__ counts,
                                                   int* __restrict__ bsum, int n) {
  __shared__ int s[1024];
  int t = threadIdx.x;
  int i = blockIdx.x * 1024 + t;
  s[t] = (i < n) ? counts[i] : 0;
  __syncthreads();
  for (int off = 512; off > 0; off >>= 1) {
    if (t < off) s[t] += s[t + off];
    __syncthreads();
  }
  if (t == 0) bsum[blockIdx.x] = s[0];
}

// Pass 2: single-block exclusive scan over nb (<=1024) block sums, in place.
__global__ __launch_bounds__(1024) void scan_bsums(int* __restrict__ bsum, int nb) {
  __shared__ int s[1024];
  int t = threadIdx.x;
  int v = (t < nb) ? bsum[t] : 0;
  s[t] = v;
  __syncthreads();
  for (int off = 1; off < 1024; off <<= 1) {
    int u = (t >= off) ? s[t - off] : 0;
    __syncthreads();
    s[t] += u;
    __syncthreads();
  }
  if (t < nb) bsum[t] = s[t] - v;  // exclusive
}

// Pass 3: in-block inclusive scan + block offset -> row_ptr/cursor/dinv.
__global__ __launch_bounds__(1024) void scan_final(const int* __restrict__ counts,
                                                   const int* __restrict__ bofs,
                                                   int* __restrict__ row_ptr,
                                                   int* __restrict__ cursor,
                                                   float* __restrict__ dinv,
                                                   int n, int E) {
  __shared__ int s[1024];
  int t = threadIdx.x;
  int i = blockIdx.x * 1024 + t;
  int c = (i < n) ? counts[i] : 0;
  s[t] = c;
  __syncthreads();
  for (int off = 1; off < 1024; off <<= 1) {
    int u = (t >= off) ? s[t - off] : 0;
    __syncthreads();
    s[t] += u;
    __syncthreads();
  }
  if (i < n) {
    int excl = bofs[blockIdx.x] + s[t] - c;
    row_ptr[i] = excl;
    cursor[i] = excl;
    dinv[i] = rsqrtf(1.0f + (float)c);  // deg includes self-loop
  }
  if (i == 0) row_ptr[n] = E;
}

__global__ __launch_bounds__(256) void fill_csr(const int* __restrict__ src,
                                                const int* __restrict__ dst,
                                                int* __restrict__ cursor,
                                                int* __restrict__ pairs, int E) {
  int e = blockIdx.x * blockDim.x + threadIdx.x;
  if (e < E) {
    int s = src[e];
    int pos = atomicAdd(&cursor[dst[e]], 1);
    pairs[pos] = s;
  }
}

// xs[i] = dinv[i] * x[i] in fp16 (vectorized, 4 floats/thread); also zeros
// the sentinel row `nrow` of both xs and hs.
__global__ __launch_bounds__(256) void cast_scale(const float* __restrict__ x,
                                                  const float* __restrict__ dinv,
                                                  __half* __restrict__ xs,
                                                  __half* __restrict__ hs,
                                                  int n4, int nrow) {
  int i = blockIdx.x * blockDim.x + threadIdx.x;
  if (i < n4) {
    float4 v = ((const float4*)x)[i];
    float d = dinv[i >> 4];
    __half2* o = (__half2*)(xs + (size_t)i * 4);
    o[0] = __floats2half2_rn(d * v.x, d * v.y);
    o[1] = __floats2half2_rn(d * v.z, d * v.w);
  } else if (i < n4 + 32) {
    int j = i - n4;
    if (j < 16)
      ((float2*)(xs + (size_t)nrow * 64))[j] = make_float2(0.f, 0.f);
    else
      ((float2*)(hs + (size_t)nrow * 64))[j - 16] = make_float2(0.f, 0.f);
  }
}

// Layer 1: y = dinv_i * (sum_e xs[src] + xs[i]); hs = half(dinv_i*relu(y@W1+b1)).
// One wave per row; lane = 8*g + q: group g handles edge slot g (8 edges in
// flight), lane loads 16B = 8 halves covering features q*8 .. q*8+7.
__global__ __launch_bounds__(256) void agg_layer1(const __half* __restrict__ xs,
                                                  const int* __restrict__ pairs,
                                                  const int* __restrict__ row_ptr,
                                                  const float* __restrict__ W1,
                                                  const float* __restrict__ b1,
                                                  __half* __restrict__ hs, int n) {
  const int lane = threadIdx.x & 63;
  const int g = lane >> 3;  // edge slot 0..7
  const int q = lane & 7;   // feature octet
  float w[64];
#pragma unroll
  for (int k = 0; k < 64; ++k) w[k] = W1[k * 64 + lane];  // column `lane`
  const float bias = b1[lane];

  int wid = blockIdx.x * (blockDim.x >> 6) + (threadIdx.x >> 6);
  int nw = gridDim.x * (blockDim.x >> 6);
  for (int i = wid; i < n; i += nw) {
    const int start = row_ptr[i];
    const int end = row_ptr[i + 1];
    float a0 = 0, a1 = 0, a2 = 0, a3 = 0, a4 = 0, a5 = 0, a6 = 0, a7 = 0;
    for (int base = start; base < end; base += 8) {
      int idx = n;  // tail: sentinel zero row
      if (base + g < end) idx = pairs[base + g];
      const float4 r = *(const float4*)(xs + (size_t)idx * 64 + q * 8);
      const __half2* hp = (const __half2*)&r;
      float2 f0 = __half22float2(hp[0]), f1 = __half22float2(hp[1]);
      float2 f2 = __half22float2(hp[2]), f3 = __half22float2(hp[3]);
      a0 += f0.x; a1 += f0.y; a2 += f1.x; a3 += f1.y;
      a4 += f2.x; a5 += f2.y; a6 += f3.x; a7 += f3.y;
    }
    // reduce the 8 edge-groups: butterfly over lane^8, ^16, ^32
#pragma unroll
    for (int off = 8; off <= 32; off <<= 1) {
      a0 += __shfl_xor(a0, off); a1 += __shfl_xor(a1, off);
      a2 += __shfl_xor(a2, off); a3 += __shfl_xor(a3, off);
      a4 += __shfl_xor(a4, off); a5 += __shfl_xor(a5, off);
      a6 += __shfl_xor(a6, off); a7 += __shfl_xor(a7, off);
    }
    const float di = rsqrtf((float)(1 + end - start));
    // self term: + xs[i] (already dinv_i-scaled)
    const float4 r = *(const float4*)(xs + (size_t)i * 64 + q * 8);
    const __half2* hp = (const __half2*)&r;
    float2 s0 = __half22float2(hp[0]), s1 = __half22float2(hp[1]);
    float2 s2 = __half22float2(hp[2]), s3 = __half22float2(hp[3]);
    float y0 = di * (a0 + s0.x), y1 = di * (a1 + s0.y);
    float y2 = di * (a2 + s1.x), y3 = di * (a3 + s1.y);
    float y4 = di * (a4 + s2.x), y5 = di * (a5 + s2.y);
    float y6 = di * (a6 + s3.x), y7 = di * (a7 + s3.y);
    // dense epilogue: out[lane] = b1[lane] + sum_k y[k] * W1[k][lane]
    // feature k = 8*kq + c lives (identically in all groups) in lane kq.
    float out = bias;
#pragma unroll
    for (int kq = 0; kq < 8; ++kq) {
      out += __shfl(y0, kq) * w[8 * kq + 0];
      out += __shfl(y1, kq) * w[8 * kq + 1];
      out += __shfl(y2, kq) * w[8 * kq + 2];
      out += __shfl(y3, kq) * w[8 * kq + 3];
      out += __shfl(y4, kq) * w[8 * kq + 4];
      out += __shfl(y5, kq) * w[8 * kq + 5];
      out += __shfl(y6, kq) * w[8 * kq + 6];
      out += __shfl(y7, kq) * w[8 * kq + 7];
    }
    hs[(size_t)i * 64 + lane] = __float2half(di * fmaxf(out, 0.f));
  }
}

// Layer 2: y = dinv_i * (sum_e hs[src] + hs[i]);
// mu = y@Wmu + bmu (lanes 0-31), lv = y@Wlv + blv (lanes 32-63).
__global__ __launch_bounds__(256) void agg_layer2(const __half* __restrict__ hs,
                                                  const int* __restrict__ pairs,
                                                  const int* __restrict__ row_ptr,
                                                  const float* __restrict__ Wmu,
                                                  const float* __restrict__ bmu,
                                                  const float* __restrict__ Wlv,
                                                  const float* __restrict__ blv,
                                                  float* __restrict__ out_mu,
                                                  float* __restrict__ out_lv, int n) {
  const int lane = threadIdx.x & 63;
  const int g = lane >> 3;
  const int q = lane & 7;
  const int col = lane & 31;
  const float* Wsel = (lane < 32) ? Wmu : Wlv;
  float w[64];
#pragma unroll
  for (int k = 0; k < 64; ++k) w[k] = Wsel[k * 32 + col];
  const float bias = (lane < 32) ? bmu[col] : blv[col];

  int wid = blockIdx.x * (blockDim.x >> 6) + (threadIdx.x >> 6);
  int nw = gridDim.x * (blockDim.x >> 6);
  for (int i = wid; i < n; i += nw) {
    const int start = row_ptr[i];
    const int end = row_ptr[i + 1];
    float a0 = 0, a1 = 0, a2 = 0, a3 = 0, a4 = 0, a5 = 0, a6 = 0, a7 = 0;
    for (int base = start; base < end; base += 8) {
      int idx = n;
      if (base + g < end) idx = pairs[base + g];
      const float4 r = *(const float4*)(hs + (size_t)idx * 64 + q * 8);
      const __half2* hp = (const __half2*)&r;
      float2 f0 = __half22float2(hp[0]), f1 = __half22float2(hp[1]);
      float2 f2 = __half22float2(hp[2]), f3 = __half22float2(hp[3]);
      a0 += f0.x; a1 += f0.y; a2 += f1.x; a3 += f1.y;
      a4 += f2.x; a5 += f2.y; a6 += f3.x; a7 += f3.y;
    }
#pragma unroll
    for (int off = 8; off <= 32; off <<= 1) {
      a0 += __shfl_xor(a0, off); a1 += __shfl_xor(a1, off);
      a2 += __shfl_xor(a2, off); a3 += __shfl_xor(a3, off);
      a4 += __shfl_xor(a4, off); a5 += __shfl_xor(a5, off);
      a6 += __shfl_xor(a6, off); a7 += __shfl_xor(a7, off);
    }
    const float di = rsqrtf((float)(1 + end - start));
    const float4 r = *(const float4*)(hs + (size_t)i * 64 + q * 8);
    const __half2* hp = (const __half2*)&r;
    float2 s0 = __half22float2(hp[0]), s1 = __half22float2(hp[1]);
    float2 s2 = __half22float2(hp[2]), s3 = __half22float2(hp[3]);
    float y0 = di * (a0 + s0.x), y1 = di * (a1 + s0.y);
    float y2 = di * (a2 + s1.x), y3 = di * (a3 + s1.y);
    float y4 = di * (a4 + s2.x), y5 = di * (a5 + s2.y);
    float y6 = di * (a6 + s3.x), y7 = di * (a7 + s3.y);
    float out = bias;
#pragma unroll
    for (int kq = 0; kq < 8; ++kq) {
      out += __shfl(y0, kq) * w[8 * kq + 0];
      out += __shfl(y1, kq) * w[8 * kq + 1];
      out += __shfl(y2, kq) * w[8 * kq + 2];
      out += __shfl(y3, kq) * w[8 * kq + 3];
      out += __shfl(y4, kq) * w[8 * kq + 4];
      out += __shfl(y5, kq) * w[8 * kq + 5];
      out += __shfl(y6, kq) * w[8 * kq + 6];
      out += __shfl(y7, kq) * w[8 * kq + 7];
    }
    if (lane < 32)
      out_mu[(size_t)i * 32 + col] = out;
    else
      out_lv[(size_t)i * 32 + col] = out;
  }
}

extern "C" void kernel_launch(void* const* d_in, const int* in_sizes, int n_in,
                              void* d_out, int out_size, void* d_ws, size_t ws_size,
                              hipStream_t stream) {
  const float* x = (const float*)d_in[0];
  const int* ei = (const int*)d_in[1];  // [2, E] row-major int32
  const float* W1 = (const float*)d_in[2];
  const float* b1 = (const float*)d_in[3];
  const float* Wmu = (const float*)d_in[4];
  const float* bmu = (const float*)d_in[5];
  const float* Wlv = (const float*)d_in[6];
  const float* blv = (const float*)d_in[7];

  const int N = in_sizes[0] / 64;
  const int E = in_sizes[1] / 2;
  const int* src = ei;
  const int* dst = ei + E;

  auto align256 = [](size_t v) { return (v + 255) & ~(size_t)255; };
  char* p = (char*)d_ws;
  int* counts = (int*)p;    p += align256((size_t)N * 4);
  int* row_ptr = (int*)p;   p += align256((size_t)(N + 1) * 4);
  int* cursor = (int*)p;    p += align256((size_t)N * 4);
  float* dinv = (float*)p;  p += align256((size_t)N * 4);
  int* bsum = (int*)p;      p += align256((size_t)1024 * 4);
  int* pairs = (int*)p;     p += align256((size_t)E * 4);
  __half* xs = (__half*)p;  p += align256((size_t)(N + 1) * 64 * 2);
  __half* hs = (__half*)p;  p += align256((size_t)(N + 1) * 64 * 2);

  float* out_mu = (float*)d_out;
  float* out_lv = out_mu + (size_t)N * 32;

  const int NB = (N + 1023) / 1024;  // scan blocks (<=1024)
  const int n4 = N * 16;             // float4 chunks of x

  hipMemsetAsync(counts, 0, (size_t)N * 4, stream);
  count_edges<<<(E + 255) / 256, 256, 0, stream>>>(dst, counts, E);
  block_sums<<<NB, 1024, 0, stream>>>(counts, bsum, N);
  scan_bsums<<<1, 1024, 0, stream>>>(bsum, NB);
  scan_final<<<NB, 1024, 0, stream>>>(counts, bsum, row_ptr, cursor, dinv, N, E);
  cast_scale<<<(n4 + 32 + 255) / 256, 256, 0, stream>>>(x, dinv, xs, hs, n4, N);
  fill_csr<<<(E + 255) / 256, 256, 0, stream>>>(src, dst, cursor, pairs, E);

  const int blocks = 4096;  // 16384 waves grid-striding 100k rows
  agg_layer1<<<blocks, 256, 0, stream>>>(xs, pairs, row_ptr, W1, b1, hs, N);
  agg_layer2<<<blocks, 256, 0, stream>>>(hs, pairs, row_ptr, Wmu, bmu, Wlv, blv,
                                         out_mu, out_lv, N);
}

// Round 5
// 378.164 us; speedup vs baseline: 2.0748x; 1.3224x over previous
//
#include <hip/hip_runtime.h>
#include <hip/hip_fp16.h>

// GCN VGAE encoder:
//   h  = relu((A @ x) @ W1 + b1)          [associativity: A(xW) == (Ax)W]
//   mu = (A @ h) @ Wmu + bmu ; lv = (A @ h) @ Wlv + blv
// A = D^-1/2 (Adj + I) D^-1/2, deg on dst side.
//
// R5: CSR build rebuilt as a radix-style two-level scatter with ZERO global
// atomics (R4's fill_csr: 105MB writeback for a 6.4MB array = 16x line
// amplification from random 4B scatters; count_edges same pattern).
//   A0: per-8192-edge-block LDS histogram over 512-node buckets -> cnt[b][blk]
//   scan cnt -> exact (bucket,block) base offsets in tmp
//   A1: re-read edges, LDS cursors, write {src,dst} in contiguous runs
//   B-count: block per bucket, LDS node histogram -> counts[] coalesced
//   row_ptr scan; B-fill: block per bucket, LDS node cursors, pairs written
//   inside the bucket's own contiguous window (row_ptr[node0]==bucket base).
// dinv folded into gather tables (xs = dinv*x, hs = dinv*relu(...)), fp16
// tables with fp32 accumulate, 8 edges in flight per wave. hs aliases tmp.

#define BKT_SHIFT 9
#define BKT_NODES 512
#define CHUNK 8192

__device__ __forceinline__ int imin(int a, int b) { return a < b ? a : b; }

// ---------------- generic scan building blocks ----------------

// Pass 1: per-block sums (1024 elements/block).
__global__ __launch_bounds__(1024) void block_sums(const int* __restrict__ in,
                                                   int* __restrict__ bsum, int n) {
  __shared__ int s[1024];
  int t = threadIdx.x;
  int i = blockIdx.x * 1024 + t;
  s[t] = (i < n) ? in[i] : 0;
  __syncthreads();
  for (int off = 512; off > 0; off >>= 1) {
    if (t < off) s[t] += s[t + off];
    __syncthreads();
  }
  if (t == 0) bsum[blockIdx.x] = s[0];
}

// Pass 2: single-block exclusive scan over nb (<=1024) block sums, in place.
__global__ __launch_bounds__(1024) void scan_bsums(int* __restrict__ bsum, int nb) {
  __shared__ int s[1024];
  int t = threadIdx.x;
  int v = (t < nb) ? bsum[t] : 0;
  s[t] = v;
  __syncthreads();
  for (int off = 1; off < 1024; off <<= 1) {
    int u = (t >= off) ? s[t - off] : 0;
    __syncthreads();
    s[t] += u;
    __syncthreads();
  }
  if (t < nb) bsum[t] = s[t] - v;  // exclusive
}

// Pass 3a: in-place exclusive scan (for the (bucket,block) offset table).
__global__ __launch_bounds__(1024) void scan_apply(int* __restrict__ data,
                                                   const int* __restrict__ bofs, int n) {
  __shared__ int s[1024];
  int t = threadIdx.x;
  int i = blockIdx.x * 1024 + t;
  int c = (i < n) ? data[i] : 0;
  s[t] = c;
  __syncthreads();
  for (int off = 1; off < 1024; off <<= 1) {
    int u = (t >= off) ? s[t - off] : 0;
    __syncthreads();
    s[t] += u;
    __syncthreads();
  }
  if (i < n) data[i] = bofs[blockIdx.x] + s[t] - c;
}

// Pass 3b: specialized for node counts -> row_ptr + dinv.
__global__ __launch_bounds__(1024) void scan_final(const int* __restrict__ counts,
                                                   const int* __restrict__ bofs,
                                                   int* __restrict__ row_ptr,
                                                   float* __restrict__ dinv,
                                                   int n, int E) {
  __shared__ int s[1024];
  int t = threadIdx.x;
  int i = blockIdx.x * 1024 + t;
  int c = (i < n) ? counts[i] : 0;
  s[t] = c;
  __syncthreads();
  for (int off = 1; off < 1024; off <<= 1) {
    int u = (t >= off) ? s[t - off] : 0;
    __syncthreads();
    s[t] += u;
    __syncthreads();
  }
  if (i < n) {
    row_ptr[i] = bofs[blockIdx.x] + s[t] - c;
    dinv[i] = rsqrtf(1.0f + (float)c);  // deg includes self-loop
  }
  if (i == 0) row_ptr[n] = E;
}

// ---------------- two-level CSR build (no global atomics) ----------------

// A0: per-chunk bucket histogram -> cnt[bucket*nblk + block] (bucket-major).
__global__ __launch_bounds__(256) void bucket_count(const int* __restrict__ dst,
                                                    int* __restrict__ cnt,
                                                    int E, int nbk, int nblk) {
  __shared__ int hist[256];
  int t = threadIdx.x;
  hist[t] = 0;
  __syncthreads();
  int base = blockIdx.x * CHUNK;
  int end = imin(base + CHUNK, E);
  for (int e = base + t; e < end; e += 256) atomicAdd(&hist[dst[e] >> BKT_SHIFT], 1);
  __syncthreads();
  if (t < nbk) cnt[t * nblk + blockIdx.x] = hist[t];
}

// A1: re-read edges; LDS cursors seeded from scanned bases; each (block,
// bucket) writes a contiguous run of {src,dst} into tmp -> near-full lines.
__global__ __launch_bounds__(256) void bucket_scatter(const int* __restrict__ src,
                                                      const int* __restrict__ dst,
                                                      const int* __restrict__ ofs,
                                                      int2* __restrict__ tmp,
                                                      int E, int nbk, int nblk) {
  __shared__ int cur[256];
  int t = threadIdx.x;
  if (t < nbk) cur[t] = ofs[t * nblk + blockIdx.x];
  __syncthreads();
  int base = blockIdx.x * CHUNK;
  int end = imin(base + CHUNK, E);
  for (int e = base + t; e < end; e += 256) {
    int d = dst[e];
    int pos = atomicAdd(&cur[d >> BKT_SHIFT], 1);
    tmp[pos] = make_int2(src[e], d);
  }
}

// B-count: one block per bucket; LDS histogram over its 512 nodes; coalesced
// counts[] write. Replaces the random-atomic count_edges.
__global__ __launch_bounds__(256) void bucket_node_count(const int2* __restrict__ tmp,
                                                         const int* __restrict__ ofs,
                                                         int* __restrict__ counts,
                                                         int n, int nbk, int nblk, int E) {
  __shared__ int hist[BKT_NODES];
  const int b = blockIdx.x;
  const int t = threadIdx.x;
  const int node0 = b << BKT_SHIFT;
  for (int j = t; j < BKT_NODES; j += 256) hist[j] = 0;
  __syncthreads();
  const int s = ofs[b * nblk];
  const int e = (b + 1 < nbk) ? ofs[(b + 1) * nblk] : E;
  for (int k = s + t; k < e; k += 256) atomicAdd(&hist[tmp[k].y - node0], 1);
  __syncthreads();
  for (int j = t; j < BKT_NODES; j += 256) {
    int node = node0 + j;
    if (node < n) counts[node] = hist[j];
  }
}

// B-fill: one block per bucket; LDS node cursors from row_ptr; writes land in
// the bucket's contiguous pairs window [row_ptr[node0], row_ptr[node_end]).
__global__ __launch_bounds__(256) void bucket_fill(const int2* __restrict__ tmp,
                                                   const int* __restrict__ ofs,
                                                   const int* __restrict__ row_ptr,
                                                   int* __restrict__ pairs,
                                                   int n, int nbk, int nblk, int E) {
  __shared__ int cur[BKT_NODES];
  const int b = blockIdx.x;
  const int t = threadIdx.x;
  const int node0 = b << BKT_SHIFT;
  for (int j = t; j < BKT_NODES; j += 256) {
    int node = node0 + j;
    cur[j] = (node < n) ? row_ptr[node] : 0;
  }
  __syncthreads();
  const int s = ofs[b * nblk];
  const int e = (b + 1 < nbk) ? ofs[(b + 1) * nblk] : E;
  for (int k = s + t; k < e; k += 256) {
    int2 p = tmp[k];
    int pos = atomicAdd(&cur[p.y - node0], 1);
    pairs[pos] = p.x;
  }
}

// ---------------- table prep + aggregation ----------------

// xs[i] = dinv[i] * x[i] in fp16; zeros sentinel row `nrow` of xs and hs.
__global__ __launch_bounds__(256) void cast_scale(const float* __restrict__ x,
                                                  const float* __restrict__ dinv,
                                                  __half* __restrict__ xs,
                                                  __half* __restrict__ hs,
                                                  int n4, int nrow) {
  int i = blockIdx.x * blockDim.x + threadIdx.x;
  if (i < n4) {
    float4 v = ((const float4*)x)[i];
    float d = dinv[i >> 4];
    __half2* o = (__half2*)(xs + (size_t)i * 4);
    o[0] = __floats2half2_rn(d * v.x, d * v.y);
    o[1] = __floats2half2_rn(d * v.z, d * v.w);
  } else if (i < n4 + 32) {
    int j = i - n4;
    if (j < 16)
      ((float2*)(xs + (size_t)nrow * 64))[j] = make_float2(0.f, 0.f);
    else
      ((float2*)(hs + (size_t)nrow * 64))[j - 16] = make_float2(0.f, 0.f);
  }
}

// Layer 1: y = dinv_i*(sum_e xs[src] + xs[i]); hs = half(dinv_i*relu(y@W1+b1)).
// One wave per row; lane = 8*g + q: 8 edges in flight, 16B (8 halves) per lane.
__global__ __launch_bounds__(256) void agg_layer1(const __half* __restrict__ xs,
                                                  const int* __restrict__ pairs,
                                                  const int* __restrict__ row_ptr,
                                                  const float* __restrict__ W1,
                                                  const float* __restrict__ b1,
                                                  __half* __restrict__ hs, int n) {
  const int lane = threadIdx.x & 63;
  const int g = lane >> 3;
  const int q = lane & 7;
  float w[64];
#pragma unroll
  for (int k = 0; k < 64; ++k) w[k] = W1[k * 64 + lane];
  const float bias = b1[lane];

  int wid = blockIdx.x * (blockDim.x >> 6) + (threadIdx.x >> 6);
  int nw = gridDim.x * (blockDim.x >> 6);
  for (int i = wid; i < n; i += nw) {
    const int start = row_ptr[i];
    const int end = row_ptr[i + 1];
    float a0 = 0, a1 = 0, a2 = 0, a3 = 0, a4 = 0, a5 = 0, a6 = 0, a7 = 0;
    for (int base = start; base < end; base += 8) {
      int idx = n;  // tail: sentinel zero row
      if (base + g < end) idx = pairs[base + g];
      const float4 r = *(const float4*)(xs + (size_t)idx * 64 + q * 8);
      const __half2* hp = (const __half2*)&r;
      float2 f0 = __half22float2(hp[0]), f1 = __half22float2(hp[1]);
      float2 f2 = __half22float2(hp[2]), f3 = __half22float2(hp[3]);
      a0 += f0.x; a1 += f0.y; a2 += f1.x; a3 += f1.y;
      a4 += f2.x; a5 += f2.y; a6 += f3.x; a7 += f3.y;
    }
#pragma unroll
    for (int off = 8; off <= 32; off <<= 1) {
      a0 += __shfl_xor(a0, off); a1 += __shfl_xor(a1, off);
      a2 += __shfl_xor(a2, off); a3 += __shfl_xor(a3, off);
      a4 += __shfl_xor(a4, off); a5 += __shfl_xor(a5, off);
      a6 += __shfl_xor(a6, off); a7 += __shfl_xor(a7, off);
    }
    const float di = rsqrtf((float)(1 + end - start));
    const float4 r = *(const float4*)(xs + (size_t)i * 64 + q * 8);
    const __half2* hp = (const __half2*)&r;
    float2 s0 = __half22float2(hp[0]), s1 = __half22float2(hp[1]);
    float2 s2 = __half22float2(hp[2]), s3 = __half22float2(hp[3]);
    float y0 = di * (a0 + s0.x), y1 = di * (a1 + s0.y);
    float y2 = di * (a2 + s1.x), y3 = di * (a3 + s1.y);
    float y4 = di * (a4 + s2.x), y5 = di * (a5 + s2.y);
    float y6 = di * (a6 + s3.x), y7 = di * (a7 + s3.y);
    float out = bias;
#pragma unroll
    for (int kq = 0; kq < 8; ++kq) {
      out += __shfl(y0, kq) * w[8 * kq + 0];
      out += __shfl(y1, kq) * w[8 * kq + 1];
      out += __shfl(y2, kq) * w[8 * kq + 2];
      out += __shfl(y3, kq) * w[8 * kq + 3];
      out += __shfl(y4, kq) * w[8 * kq + 4];
      out += __shfl(y5, kq) * w[8 * kq + 5];
      out += __shfl(y6, kq) * w[8 * kq + 6];
      out += __shfl(y7, kq) * w[8 * kq + 7];
    }
    hs[(size_t)i * 64 + lane] = __float2half(di * fmaxf(out, 0.f));
  }
}

// Layer 2: y = dinv_i*(sum_e hs[src] + hs[i]);
// mu = y@Wmu + bmu (lanes 0-31), lv = y@Wlv + blv (lanes 32-63).
__global__ __launch_bounds__(256) void agg_layer2(const __half* __restrict__ hs,
                                                  const int* __restrict__ pairs,
                                                  const int* __restrict__ row_ptr,
                                                  const float* __restrict__ Wmu,
                                                  const float* __restrict__ bmu,
                                                  const float* __restrict__ Wlv,
                                                  const float* __restrict__ blv,
                                                  float* __restrict__ out_mu,
                                                  float* __restrict__ out_lv, int n) {
  const int lane = threadIdx.x & 63;
  const int g = lane >> 3;
  const int q = lane & 7;
  const int col = lane & 31;
  const float* Wsel = (lane < 32) ? Wmu : Wlv;
  float w[64];
#pragma unroll
  for (int k = 0; k < 64; ++k) w[k] = Wsel[k * 32 + col];
  const float bias = (lane < 32) ? bmu[col] : blv[col];

  int wid = blockIdx.x * (blockDim.x >> 6) + (threadIdx.x >> 6);
  int nw = gridDim.x * (blockDim.x >> 6);
  for (int i = wid; i < n; i += nw) {
    const int start = row_ptr[i];
    const int end = row_ptr[i + 1];
    float a0 = 0, a1 = 0, a2 = 0, a3 = 0, a4 = 0, a5 = 0, a6 = 0, a7 = 0;
    for (int base = start; base < end; base += 8) {
      int idx = n;
      if (base + g < end) idx = pairs[base + g];
      const float4 r = *(const float4*)(hs + (size_t)idx * 64 + q * 8);
      const __half2* hp = (const __half2*)&r;
      float2 f0 = __half22float2(hp[0]), f1 = __half22float2(hp[1]);
      float2 f2 = __half22float2(hp[2]), f3 = __half22float2(hp[3]);
      a0 += f0.x; a1 += f0.y; a2 += f1.x; a3 += f1.y;
      a4 += f2.x; a5 += f2.y; a6 += f3.x; a7 += f3.y;
    }
#pragma unroll
    for (int off = 8; off <= 32; off <<= 1) {
      a0 += __shfl_xor(a0, off); a1 += __shfl_xor(a1, off);
      a2 += __shfl_xor(a2, off); a3 += __shfl_xor(a3, off);
      a4 += __shfl_xor(a4, off); a5 += __shfl_xor(a5, off);
      a6 += __shfl_xor(a6, off); a7 += __shfl_xor(a7, off);
    }
    const float di = rsqrtf((float)(1 + end - start));
    const float4 r = *(const float4*)(hs + (size_t)i * 64 + q * 8);
    const __half2* hp = (const __half2*)&r;
    float2 s0 = __half22float2(hp[0]), s1 = __half22float2(hp[1]);
    float2 s2 = __half22float2(hp[2]), s3 = __half22float2(hp[3]);
    float y0 = di * (a0 + s0.x), y1 = di * (a1 + s0.y);
    float y2 = di * (a2 + s1.x), y3 = di * (a3 + s1.y);
    float y4 = di * (a4 + s2.x), y5 = di * (a5 + s2.y);
    float y6 = di * (a6 + s3.x), y7 = di * (a7 + s3.y);
    float out = bias;
#pragma unroll
    for (int kq = 0; kq < 8; ++kq) {
      out += __shfl(y0, kq) * w[8 * kq + 0];
      out += __shfl(y1, kq) * w[8 * kq + 1];
      out += __shfl(y2, kq) * w[8 * kq + 2];
      out += __shfl(y3, kq) * w[8 * kq + 3];
      out += __shfl(y4, kq) * w[8 * kq + 4];
      out += __shfl(y5, kq) * w[8 * kq + 5];
      out += __shfl(y6, kq) * w[8 * kq + 6];
      out += __shfl(y7, kq) * w[8 * kq + 7];
    }
    if (lane < 32)
      out_mu[(size_t)i * 32 + col] = out;
    else
      out_lv[(size_t)i * 32 + col] = out;
  }
}

extern "C" void kernel_launch(void* const* d_in, const int* in_sizes, int n_in,
                              void* d_out, int out_size, void* d_ws, size_t ws_size,
                              hipStream_t stream) {
  const float* x = (const float*)d_in[0];
  const int* ei = (const int*)d_in[1];  // [2, E] row-major int32
  const float* W1 = (const float*)d_in[2];
  const float* b1 = (const float*)d_in[3];
  const float* Wmu = (const float*)d_in[4];
  const float* bmu = (const float*)d_in[5];
  const float* Wlv = (const float*)d_in[6];
  const float* blv = (const float*)d_in[7];

  const int N = in_sizes[0] / 64;
  const int E = in_sizes[1] / 2;
  const int* src = ei;
  const int* dst = ei + E;

  const int NBK = (N + BKT_NODES - 1) >> BKT_SHIFT;   // 196 buckets (<=256)
  const int NBLK = (E + CHUNK - 1) / CHUNK;           // 196 A-blocks
  const int FL = NBK * NBLK;                          // offset-table length

  auto align256 = [](size_t v) { return (v + 255) & ~(size_t)255; };
  char* p = (char*)d_ws;
  int* counts = (int*)p;   p += align256((size_t)N * 4);
  int* row_ptr = (int*)p;  p += align256((size_t)(N + 1) * 4);
  float* dinv = (float*)p; p += align256((size_t)N * 4);
  int* bsum = (int*)p;     p += align256((size_t)1024 * 4);
  int* cnt = (int*)p;      p += align256((size_t)FL * 4);  // -> offsets after scan
  int* pairs = (int*)p;    p += align256((size_t)E * 4);
  __half* xs = (__half*)p; p += align256((size_t)(N + 1) * 64 * 2);
  size_t tmp_bytes = (size_t)E * 8;
  size_t hs_bytes = (size_t)(N + 1) * 64 * 2;
  int2* tmp = (int2*)p;    // union: tmp dead after bucket_fill; hs written later
  __half* hs = (__half*)p; p += align256(tmp_bytes > hs_bytes ? tmp_bytes : hs_bytes);

  float* out_mu = (float*)d_out;
  float* out_lv = out_mu + (size_t)N * 32;

  const int NB_N = (N + 1023) / 1024;    // scan blocks for counts
  const int NB_F = (FL + 1023) / 1024;   // scan blocks for cnt table
  const int n4 = N * 16;                 // float4 chunks of x

  // --- CSR build (no global atomics) ---
  bucket_count<<<NBLK, 256, 0, stream>>>(dst, cnt, E, NBK, NBLK);
  block_sums<<<NB_F, 1024, 0, stream>>>(cnt, bsum, FL);
  scan_bsums<<<1, 1024, 0, stream>>>(bsum, NB_F);
  scan_apply<<<NB_F, 1024, 0, stream>>>(cnt, bsum, FL);
  bucket_scatter<<<NBLK, 256, 0, stream>>>(src, dst, cnt, tmp, E, NBK, NBLK);
  bucket_node_count<<<NBK, 256, 0, stream>>>(tmp, cnt, counts, N, NBK, NBLK, E);
  block_sums<<<NB_N, 1024, 0, stream>>>(counts, bsum, N);
  scan_bsums<<<1, 1024, 0, stream>>>(bsum, NB_N);
  scan_final<<<NB_N, 1024, 0, stream>>>(counts, bsum, row_ptr, dinv, N, E);
  bucket_fill<<<NBK, 256, 0, stream>>>(tmp, cnt, row_ptr, pairs, N, NBK, NBLK, E);

  // --- tables (after bucket_fill: hs aliases tmp) ---
  cast_scale<<<(n4 + 32 + 255) / 256, 256, 0, stream>>>(x, dinv, xs, hs, n4, N);

  // --- aggregation + fused dense layers ---
  const int blocks = 4096;  // 16384 waves grid-striding 100k rows
  agg_layer1<<<blocks, 256, 0, stream>>>(xs, pairs, row_ptr, W1, b1, hs, N);
  agg_layer2<<<blocks, 256, 0, stream>>>(hs, pairs, row_ptr, Wmu, bmu, Wlv, blv,
                                         out_mu, out_lv, N);
}

// Round 6
// 307.645 us; speedup vs baseline: 2.5504x; 1.2292x over previous
//
#include <hip/hip_runtime.h>
#include <hip/hip_fp16.h>

// GCN VGAE encoder:
//   h  = relu((A @ x) @ W1 + b1)          [associativity: A(xW) == (Ax)W]
//   mu = (A @ h) @ Wmu + bmu ; lv = (A @ h) @ Wlv + blv
// A = D^-1/2 (Adj + I) D^-1/2, deg on dst side. dinv folded into tables:
//   xs[s]=dinv_s*x[s]; hs[i]=dinv_i*relu(...); y_i = dinv_i*(sum_e xs[src]+xs[i])
//
// R6: (a) agg epilogue via MFMA: 16 rows/wave, gather partials folded once
// (xor-32), di-scaled, fp16 -> wave-private LDS 16x256 A-tile (K'=256: the
// remaining 4-group reduction rides the MFMA K-dim, B = W replicated over
// groups). 8 mfma_f32_16x16x32_f16 per 16 rows replaces ~1400 DS ops (R5:
// 88 shfl/row => DS-pipe ~40% busy). Row stride 264 halves => 2-way banks.
// (b) pairs prefetch breaks the pairs->gather serial chain.
// (c) CSR: bucket_build fuses node-hist + LDS scan + row_ptr/dinv + fill
// (replaces 4 kernels; zero global atomics anywhere).

#define BKT_SHIFT 9
#define BKT_NODES 512
#define CHUNK 8192

typedef __attribute__((ext_vector_type(8))) _Float16 half8;
typedef __attribute__((ext_vector_type(4))) float float4v;

__device__ __forceinline__ int imin(int a, int b) { return a < b ? a : b; }

// ---------------- scan building blocks (for the (bucket,block) table) ------

__global__ __launch_bounds__(1024) void block_sums(const int* __restrict__ in,
                                                   int* __restrict__ bsum, int n) {
  __shared__ int s[1024];
  int t = threadIdx.x;
  int i = blockIdx.x * 1024 + t;
  s[t] = (i < n) ? in[i] : 0;
  __syncthreads();
  for (int off = 512; off > 0; off >>= 1) {
    if (t < off) s[t] += s[t + off];
    __syncthreads();
  }
  if (t == 0) bsum[blockIdx.x] = s[0];
}

__global__ __launch_bounds__(1024) void scan_bsums(int* __restrict__ bsum, int nb) {
  __shared__ int s[1024];
  int t = threadIdx.x;
  int v = (t < nb) ? bsum[t] : 0;
  s[t] = v;
  __syncthreads();
  for (int off = 1; off < 1024; off <<= 1) {
    int u = (t >= off) ? s[t - off] : 0;
    __syncthreads();
    s[t] += u;
    __syncthreads();
  }
  if (t < nb) bsum[t] = s[t] - v;  // exclusive
}

__global__ __launch_bounds__(1024) void scan_apply(int* __restrict__ data,
                                                   const int* __restrict__ bofs, int n) {
  __shared__ int s[1024];
  int t = threadIdx.x;
  int i = blockIdx.x * 1024 + t;
  int c = (i < n) ? data[i] : 0;
  s[t] = c;
  __syncthreads();
  for (int off = 1; off < 1024; off <<= 1) {
    int u = (t >= off) ? s[t - off] : 0;
    __syncthreads();
    s[t] += u;
    __syncthreads();
  }
  if (i < n) data[i] = bofs[blockIdx.x] + s[t] - c;
}

// ---------------- two-level CSR build (no global atomics) ------------------

// A0: per-chunk bucket histogram -> cnt[bucket*nblk + block] (bucket-major).
__global__ __launch_bounds__(256) void bucket_count(const int* __restrict__ dst,
                                                    int* __restrict__ cnt,
                                                    int E, int nbk, int nblk) {
  __shared__ int hist[256];
  int t = threadIdx.x;
  hist[t] = 0;
  __syncthreads();
  int base = blockIdx.x * CHUNK;
  int end = imin(base + CHUNK, E);
  for (int e = base + t; e < end; e += 256) atomicAdd(&hist[dst[e] >> BKT_SHIFT], 1);
  __syncthreads();
  if (t < nbk) cnt[t * nblk + blockIdx.x] = hist[t];
}

// A1: re-read edges; LDS cursors from scanned bases; contiguous runs to tmp.
__global__ __launch_bounds__(256) void bucket_scatter(const int* __restrict__ src,
                                                      const int* __restrict__ dst,
                                                      const int* __restrict__ ofs,
                                                      int2* __restrict__ tmp,
                                                      int E, int nbk, int nblk) {
  __shared__ int cur[256];
  int t = threadIdx.x;
  if (t < nbk) cur[t] = ofs[t * nblk + blockIdx.x];
  __syncthreads();
  int base = blockIdx.x * CHUNK;
  int end = imin(base + CHUNK, E);
  for (int e = base + t; e < end; e += 256) {
    int d = dst[e];
    int pos = atomicAdd(&cur[d >> BKT_SHIFT], 1);
    tmp[pos] = make_int2(src[e], d);
  }
}

// B: one block per bucket. LDS node histogram -> LDS scan -> row_ptr/dinv
// (coalesced) -> LDS-cursor fill of pairs inside the bucket's window.
// Fuses R5's bucket_node_count + 3-kernel N-scan + bucket_fill.
__global__ __launch_bounds__(512) void bucket_build(const int2* __restrict__ tmp,
                                                    const int* __restrict__ ofs,
                                                    int* __restrict__ row_ptr,
                                                    float* __restrict__ dinv,
                                                    int* __restrict__ pairs,
                                                    int n, int nbk, int nblk, int E) {
  __shared__ int hist[BKT_NODES];
  __shared__ int scn[BKT_NODES];
  const int b = blockIdx.x;
  const int t = threadIdx.x;
  const int node0 = b << BKT_SHIFT;
  hist[t] = 0;
  __syncthreads();
  const int s = ofs[b * nblk];
  const int e = (b + 1 < nbk) ? ofs[(b + 1) * nblk] : E;
  for (int k = s + t; k < e; k += 512) atomicAdd(&hist[tmp[k].y - node0], 1);
  __syncthreads();
  int v = hist[t];
  scn[t] = v;
  __syncthreads();
  for (int off = 1; off < 512; off <<= 1) {
    int u = (t >= off) ? scn[t - off] : 0;
    __syncthreads();
    scn[t] += u;
    __syncthreads();
  }
  int excl = s + scn[t] - v;  // exclusive prefix = CSR start of node0+t
  int node = node0 + t;
  if (node < n) {
    row_ptr[node] = excl;
    dinv[node] = rsqrtf(1.0f + (float)v);  // deg includes self-loop
  }
  if (b == nbk - 1 && t == 0) row_ptr[n] = E;
  hist[t] = excl;  // reuse as cursor
  __syncthreads();
  for (int k = s + t; k < e; k += 512) {
    int2 p = tmp[k];
    int pos = atomicAdd(&hist[p.y - node0], 1);
    pairs[pos] = p.x;
  }
}

// ---------------- table prep ----------------

// xs[i] = dinv[i] * x[i] in fp16; zeros sentinel row `nrow` of xs and hs.
__global__ __launch_bounds__(256) void cast_scale(const float* __restrict__ x,
                                                  const float* __restrict__ dinv,
                                                  __half* __restrict__ xs,
                                                  __half* __restrict__ hs,
                                                  int n4, int nrow) {
  int i = blockIdx.x * blockDim.x + threadIdx.x;
  if (i < n4) {
    float4 v = ((const float4*)x)[i];
    float d = dinv[i >> 4];
    __half2* o = (__half2*)(xs + (size_t)i * 4);
    o[0] = __floats2half2_rn(d * v.x, d * v.y);
    o[1] = __floats2half2_rn(d * v.z, d * v.w);
  } else if (i < n4 + 32) {
    int j = i - n4;
    if (j < 16)
      ((float2*)(xs + (size_t)nrow * 64))[j] = make_float2(0.f, 0.f);
    else
      ((float2*)(hs + (size_t)nrow * 64))[j - 16] = make_float2(0.f, 0.f);
  }
}

// ---------------- aggregation + fused dense via MFMA ----------------
// Wave handles 16 rows. Per row: 8-edges-in-flight gather (lane=8g+q, 16B of
// 8 halves per lane), one xor-32 fold (groups 8->4), di-scale, fp16 ->
// ylds[row][ (g&3)*64 + 8q+c ]  (A-tile, K'=256; remaining group-reduction
// happens inside MFMA K since B is W replicated over the 4 group slots).
// Then 8 k-steps x 4 n-tiles of mfma_f32_16x16x32_f16, bias in C-init.
// A layout: A[m=lane&15][k=(lane>>4)*8+j]; B[k=(lane>>4)*8+j][n=lane&15];
// C/D: col=lane&15, row=(lane>>4)*4+reg  (guide §3, m89/m120-verified).

#define YSTRIDE 264  // 256 + 8 halves pad: A-reads land 2-way on banks (free)

__global__ __launch_bounds__(256, 4) void agg_layer1(const __half* __restrict__ xs,
                                                     const int* __restrict__ pairs,
                                                     const int* __restrict__ row_ptr,
                                                     const float* __restrict__ W1,
                                                     const float* __restrict__ b1,
                                                     __half* __restrict__ hs, int n) {
  __shared__ _Float16 ylds_all[4][16 * YSTRIDE];
  __shared__ float dilds_all[4][16];
  const int wv = threadIdx.x >> 6;
  _Float16* ylds = ylds_all[wv];
  float* dilds = dilds_all[wv];
  const int lane = threadIdx.x & 63;
  const int g = lane >> 3, q = lane & 7;
  const int quad = lane >> 4, col = lane & 15;

  // B-fragments: bfrag[s][t][jj] = W1[(s*32 + quad*8 + jj)][t*16 + col]
  half8 bfrag[2][4];
#pragma unroll
  for (int s = 0; s < 2; ++s)
#pragma unroll
    for (int t = 0; t < 4; ++t)
#pragma unroll
      for (int jj = 0; jj < 8; ++jj)
        bfrag[s][t][jj] = (_Float16)W1[(s * 32 + quad * 8 + jj) * 64 + t * 16 + col];
  float bias[4];
#pragma unroll
  for (int t = 0; t < 4; ++t) bias[t] = b1[t * 16 + col];

  const int ntiles = (n + 15) >> 4;
  for (int tile = blockIdx.x * 4 + wv; tile < ntiles; tile += gridDim.x * 4) {
    const int row0 = tile << 4;
    for (int r = 0; r < 16; ++r) {
      const int i = row0 + r;
      int start = 0, end = 0;
      if (i < n) { start = row_ptr[i]; end = row_ptr[i + 1]; }
      float a0 = 0, a1 = 0, a2 = 0, a3 = 0, a4 = 0, a5 = 0, a6 = 0, a7 = 0;
      int idx = (start + g < end) ? pairs[start + g] : n;
      for (int base = start; base < end; base += 8) {
        int idxn = (base + 8 + g < end) ? pairs[base + 8 + g] : n;  // prefetch
        const float4 rr = *(const float4*)(xs + (size_t)idx * 64 + q * 8);
        const __half2* hp = (const __half2*)&rr;
        float2 f0 = __half22float2(hp[0]), f1 = __half22float2(hp[1]);
        float2 f2 = __half22float2(hp[2]), f3 = __half22float2(hp[3]);
        a0 += f0.x; a1 += f0.y; a2 += f1.x; a3 += f1.y;
        a4 += f2.x; a5 += f2.y; a6 += f3.x; a7 += f3.y;
        idx = idxn;
      }
      // self term (g==0 only; sentinel row for i>=n)
      const int iself = (i < n) ? i : n;
      const float4 sr = *(const float4*)(xs + (size_t)iself * 64 + q * 8);
      if (g == 0 && i < n) {
        const __half2* hp = (const __half2*)&sr;
        float2 f0 = __half22float2(hp[0]), f1 = __half22float2(hp[1]);
        float2 f2 = __half22float2(hp[2]), f3 = __half22float2(hp[3]);
        a0 += f0.x; a1 += f0.y; a2 += f1.x; a3 += f1.y;
        a4 += f2.x; a5 += f2.y; a6 += f3.x; a7 += f3.y;
      }
      // fold groups g and g+4
      a0 += __shfl_xor(a0, 32); a1 += __shfl_xor(a1, 32);
      a2 += __shfl_xor(a2, 32); a3 += __shfl_xor(a3, 32);
      a4 += __shfl_xor(a4, 32); a5 += __shfl_xor(a5, 32);
      a6 += __shfl_xor(a6, 32); a7 += __shfl_xor(a7, 32);
      const float di = rsqrtf((float)(1 + end - start));
      half8 yv;
      yv[0] = (_Float16)(di * a0); yv[1] = (_Float16)(di * a1);
      yv[2] = (_Float16)(di * a2); yv[3] = (_Float16)(di * a3);
      yv[4] = (_Float16)(di * a4); yv[5] = (_Float16)(di * a5);
      yv[6] = (_Float16)(di * a6); yv[7] = (_Float16)(di * a7);
      *(half8*)(ylds + r * YSTRIDE + (g & 3) * 64 + q * 8) = yv;
      if (lane == 0) dilds[r] = di;
    }
    // MFMA: D = A(16x256) * B'(256x64) + bias
    float4v acc[4];
#pragma unroll
    for (int t = 0; t < 4; ++t) acc[t] = (float4v){bias[t], bias[t], bias[t], bias[t]};
#pragma unroll
    for (int s2 = 0; s2 < 8; ++s2) {
      half8 af = *(half8*)(ylds + col * YSTRIDE + s2 * 32 + quad * 8);
      const int sW = s2 & 1;
#pragma unroll
      for (int t = 0; t < 4; ++t)
        acc[t] = __builtin_amdgcn_mfma_f32_16x16x32_f16(af, bfrag[sW][t], acc[t], 0, 0, 0);
    }
    const float4 dis = *(const float4*)(dilds + quad * 4);
    const float dd[4] = {dis.x, dis.y, dis.z, dis.w};
#pragma unroll
    for (int t = 0; t < 4; ++t)
#pragma unroll
      for (int reg = 0; reg < 4; ++reg) {
        const int row = row0 + quad * 4 + reg;
        if (row < n)
          hs[(size_t)row * 64 + t * 16 + col] =
              __float2half(dd[reg] * fmaxf(acc[t][reg], 0.f));
      }
  }
}

// Layer 2: same structure; B' = [Wmu | Wlv] (64 cols), fp32 outputs, no
// post-scale (di already folded into the A-tile; bias in C-init).
__global__ __launch_bounds__(256, 4) void agg_layer2(const __half* __restrict__ hsin,
                                                     const int* __restrict__ pairs,
                                                     const int* __restrict__ row_ptr,
                                                     const float* __restrict__ Wmu,
                                                     const float* __restrict__ bmu,
                                                     const float* __restrict__ Wlv,
                                                     const float* __restrict__ blv,
                                                     float* __restrict__ out_mu,
                                                     float* __restrict__ out_lv, int n) {
  __shared__ _Float16 ylds_all[4][16 * YSTRIDE];
  const int wv = threadIdx.x >> 6;
  _Float16* ylds = ylds_all[wv];
  const int lane = threadIdx.x & 63;
  const int g = lane >> 3, q = lane & 7;
  const int quad = lane >> 4, col = lane & 15;

  half8 bfrag[2][4];
#pragma unroll
  for (int s = 0; s < 2; ++s)
#pragma unroll
    for (int t = 0; t < 4; ++t) {
      const int j = t * 16 + col;
      const float* W = (j < 32) ? Wmu : Wlv;
      const int jc = j & 31;
#pragma unroll
      for (int jj = 0; jj < 8; ++jj)
        bfrag[s][t][jj] = (_Float16)W[(s * 32 + quad * 8 + jj) * 32 + jc];
    }
  float bias[4];
#pragma unroll
  for (int t = 0; t < 4; ++t) {
    const int j = t * 16 + col;
    bias[t] = (j < 32) ? bmu[j] : blv[j - 32];
  }

  const int ntiles = (n + 15) >> 4;
  for (int tile = blockIdx.x * 4 + wv; tile < ntiles; tile += gridDim.x * 4) {
    const int row0 = tile << 4;
    for (int r = 0; r < 16; ++r) {
      const int i = row0 + r;
      int start = 0, end = 0;
      if (i < n) { start = row_ptr[i]; end = row_ptr[i + 1]; }
      float a0 = 0, a1 = 0, a2 = 0, a3 = 0, a4 = 0, a5 = 0, a6 = 0, a7 = 0;
      int idx = (start + g < end) ? pairs[start + g] : n;
      for (int base = start; base < end; base += 8) {
        int idxn = (base + 8 + g < end) ? pairs[base + 8 + g] : n;
        const float4 rr = *(const float4*)(hsin + (size_t)idx * 64 + q * 8);
        const __half2* hp = (const __half2*)&rr;
        float2 f0 = __half22float2(hp[0]), f1 = __half22float2(hp[1]);
        float2 f2 = __half22float2(hp[2]), f3 = __half22float2(hp[3]);
        a0 += f0.x; a1 += f0.y; a2 += f1.x; a3 += f1.y;
        a4 += f2.x; a5 += f2.y; a6 += f3.x; a7 += f3.y;
        idx = idxn;
      }
      const int iself = (i < n) ? i : n;
      const float4 sr = *(const float4*)(hsin + (size_t)iself * 64 + q * 8);
      if (g == 0 && i < n) {
        const __half2* hp = (const __half2*)&sr;
        float2 f0 = __half22float2(hp[0]), f1 = __half22float2(hp[1]);
        float2 f2 = __half22float2(hp[2]), f3 = __half22float2(hp[3]);
        a0 += f0.x; a1 += f0.y; a2 += f1.x; a3 += f1.y;
        a4 += f2.x; a5 += f2.y; a6 += f3.x; a7 += f3.y;
      }
      a0 += __shfl_xor(a0, 32); a1 += __shfl_xor(a1, 32);
      a2 += __shfl_xor(a2, 32); a3 += __shfl_xor(a3, 32);
      a4 += __shfl_xor(a4, 32); a5 += __shfl_xor(a5, 32);
      a6 += __shfl_xor(a6, 32); a7 += __shfl_xor(a7, 32);
      const float di = rsqrtf((float)(1 + end - start));
      half8 yv;
      yv[0] = (_Float16)(di * a0); yv[1] = (_Float16)(di * a1);
      yv[2] = (_Float16)(di * a2); yv[3] = (_Float16)(di * a3);
      yv[4] = (_Float16)(di * a4); yv[5] = (_Float16)(di * a5);
      yv[6] = (_Float16)(di * a6); yv[7] = (_Float16)(di * a7);
      *(half8*)(ylds + r * YSTRIDE + (g & 3) * 64 + q * 8) = yv;
    }
    float4v acc[4];
#pragma unroll
    for (int t = 0; t < 4; ++t) acc[t] = (float4v){bias[t], bias[t], bias[t], bias[t]};
#pragma unroll
    for (int s2 = 0; s2 < 8; ++s2) {
      half8 af = *(half8*)(ylds + col * YSTRIDE + s2 * 32 + quad * 8);
      const int sW = s2 & 1;
#pragma unroll
      for (int t = 0; t < 4; ++t)
        acc[t] = __builtin_amdgcn_mfma_f32_16x16x32_f16(af, bfrag[sW][t], acc[t], 0, 0, 0);
    }
#pragma unroll
    for (int t = 0; t < 4; ++t)
#pragma unroll
      for (int reg = 0; reg < 4; ++reg) {
        const int row = row0 + quad * 4 + reg;
        if (row < n) {
          const int j = t * 16 + col;
          if (j < 32)
            out_mu[(size_t)row * 32 + j] = acc[t][reg];
          else
            out_lv[(size_t)row * 32 + (j - 32)] = acc[t][reg];
        }
      }
  }
}

extern "C" void kernel_launch(void* const* d_in, const int* in_sizes, int n_in,
                              void* d_out, int out_size, void* d_ws, size_t ws_size,
                              hipStream_t stream) {
  const float* x = (const float*)d_in[0];
  const int* ei = (const int*)d_in[1];  // [2, E] row-major int32
  const float* W1 = (const float*)d_in[2];
  const float* b1 = (const float*)d_in[3];
  const float* Wmu = (const float*)d_in[4];
  const float* bmu = (const float*)d_in[5];
  const float* Wlv = (const float*)d_in[6];
  const float* blv = (const float*)d_in[7];

  const int N = in_sizes[0] / 64;
  const int E = in_sizes[1] / 2;
  const int* src = ei;
  const int* dst = ei + E;

  const int NBK = (N + BKT_NODES - 1) >> BKT_SHIFT;  // 196 buckets (<=256)
  const int NBLK = (E + CHUNK - 1) / CHUNK;          // 196 A-blocks
  const int FL = NBK * NBLK;

  auto align256 = [](size_t v) { return (v + 255) & ~(size_t)255; };
  char* p = (char*)d_ws;
  int* row_ptr = (int*)p;  p += align256((size_t)(N + 1) * 4);
  float* dinv = (float*)p; p += align256((size_t)N * 4);
  int* bsum = (int*)p;     p += align256((size_t)1024 * 4);
  int* cnt = (int*)p;      p += align256((size_t)FL * 4);  // -> offsets after scan
  int* pairs = (int*)p;    p += align256((size_t)E * 4);
  __half* xs = (__half*)p; p += align256((size_t)(N + 1) * 64 * 2);
  size_t tmp_bytes = (size_t)E * 8;
  size_t hs_bytes = (size_t)(N + 1) * 64 * 2;
  int2* tmp = (int2*)p;    // union: tmp dead after bucket_build; hs written later
  __half* hs = (__half*)p; p += align256(tmp_bytes > hs_bytes ? tmp_bytes : hs_bytes);

  float* out_mu = (float*)d_out;
  float* out_lv = out_mu + (size_t)N * 32;

  const int NB_F = (FL + 1023) / 1024;
  const int n4 = N * 16;

  // --- CSR build (no global atomics) ---
  bucket_count<<<NBLK, 256, 0, stream>>>(dst, cnt, E, NBK, NBLK);
  block_sums<<<NB_F, 1024, 0, stream>>>(cnt, bsum, FL);
  scan_bsums<<<1, 1024, 0, stream>>>(bsum, NB_F);
  scan_apply<<<NB_F, 1024, 0, stream>>>(cnt, bsum, FL);
  bucket_scatter<<<NBLK, 256, 0, stream>>>(src, dst, cnt, tmp, E, NBK, NBLK);
  bucket_build<<<NBK, 512, 0, stream>>>(tmp, cnt, row_ptr, dinv, pairs, N, NBK, NBLK, E);

  // --- tables (after bucket_build: hs aliases tmp) ---
  cast_scale<<<(n4 + 32 + 255) / 256, 256, 0, stream>>>(x, dinv, xs, hs, n4, N);

  // --- aggregation + fused dense layers (MFMA epilogue) ---
  const int ntiles = (N + 15) / 16;
  const int ablocks = (ntiles + 3) / 4;  // 1 tile (16 rows) per wave
  agg_layer1<<<ablocks, 256, 0, stream>>>(xs, pairs, row_ptr, W1, b1, hs, N);
  agg_layer2<<<ablocks, 256, 0, stream>>>(hs, pairs, row_ptr, Wmu, bmu, Wlv, blv,
                                          out_mu, out_lv, N);
}